// Round 1
// baseline (271.856 us; speedup 1.0000x reference)
//
#include <hip/hip_runtime.h>
#include <math.h>

#define NB 64
#define NA 5
#define NC 80
#define NH 38
#define NW 38
#define MAXB 50
#define PLANE (NH*NW)          // 1444
#define PER_B (NA*PLANE)       // 7220
#define NCH (5+NC)             // 85

__constant__ float c_aw[5] = {1.3221f, 3.19275f, 5.05587f, 9.47112f, 11.2364f};
__constant__ float c_ah[5] = {1.73145f, 4.00944f, 8.09892f, 4.84053f, 10.0071f};

struct Entry {
    int   fidx;    // global flat index into N, or -1 if not a winner
    int   tcls;
    float cm, tc0, tc1, tc2, tc3, tconf;
};

__device__ inline float sigmoidf(float x) { return 1.f / (1.f + expf(-x)); }

__device__ inline float iou_f(float ax, float ay, float aw_, float ah_,
                              float bx, float by, float bw_, float bh_) {
    float ax1 = ax - aw_ * 0.5f, ax2 = ax + aw_ * 0.5f;
    float ay1 = ay - ah_ * 0.5f, ay2 = ay + ah_ * 0.5f;
    float bx1 = bx - bw_ * 0.5f, bx2 = bx + bw_ * 0.5f;
    float by1 = by - bh_ * 0.5f, by2 = by + bh_ * 0.5f;
    float iw = fmaxf(fminf(ax2, bx2) - fmaxf(ax1, bx1), 0.f);
    float ih = fmaxf(fminf(ay2, by2) - fmaxf(ay1, by1), 0.f);
    float inter = iw * ih;
    float uni = aw_ * ah_ + bw_ * bh_ - inter;
    return inter / fmaxf(uni, 1e-10f);
}

// ---------------- Kernel A: per-batch GT prep (64 blocks x 64 threads) -----
__global__ __launch_bounds__(64)
void prep_kernel(const float* __restrict__ out, const float* __restrict__ target,
                 float4* __restrict__ gt, int* __restrict__ nvalid,
                 Entry* __restrict__ entries) {
    int b = blockIdx.x;
    int t = threadIdx.x;
    const float* tb = target + b * MAXB * 5;

    float cls = 0.f, x = 0.f, y = 0.f, w = 0.f, h = 0.f;
    bool has = (t < MAXB);
    if (has) {
        cls = tb[t * 5 + 0];
        x   = tb[t * 5 + 1];
        y   = tb[t * 5 + 2];
        w   = tb[t * 5 + 3];
        h   = tb[t * 5 + 4];
    }
    unsigned long long mask = __ballot(has && (x > 0.f));
    // valid = all boxes s<=t have x>0 (cumprod prefix)
    bool valid = has && (((~mask) & ((1ull << (t + 1)) - 1ull)) == 0ull);

    float gx = x * NW, gy = y * NH, gw = w * NW, gh = h * NH;

    // anchor argmax (first index on ties, like jnp.argmax)
    int best = 0; float bestr = -1.f;
    #pragma unroll
    for (int a = 0; a < NA; a++) {
        float inter = fminf(c_aw[a], gw) * fminf(c_ah[a], gh);
        float uni   = c_aw[a] * c_ah[a] + gw * gh - inter;
        float r = inter / fmaxf(uni, 1e-10f);
        if (r > bestr) { bestr = r; best = a; }
    }
    int gi = min(max((int)gx, 0), NW - 1);
    int gj = min(max((int)gy, 0), NH - 1);
    int fidx = b * PER_B + best * PLANE + gj * NW + gi;

    float iou_sel = 0.f;
    if (valid) {
        int base = ((b * NA + best) * NCH) * PLANE + gj * NW + gi;
        float o0 = out[base];
        float o1 = out[base + PLANE];
        float o2 = out[base + 2 * PLANE];
        float o3 = out[base + 3 * PLANE];
        float px = sigmoidf(o0) + (float)gi;
        float py = sigmoidf(o1) + (float)gj;
        float pw = expf(o2) * c_aw[best];
        float ph = expf(o3) * c_ah[best];
        iou_sel = iou_f(gx, gy, gw, gh, px, py, pw, ph);
    }

    // winner = last valid box with this fidx (numpy last-write-wins)
    __shared__ int sfidx[64];
    sfidx[t] = valid ? fidx : -1;
    __syncthreads();
    bool winner = valid;
    if (valid) {
        for (int s = t + 1; s < MAXB; s++) {
            if (sfidx[s] == fidx) { winner = false; break; }
        }
    }

    if (has) {
        gt[b * MAXB + t] = make_float4(gx, gy, gw, gh);
        Entry e;
        e.fidx  = winner ? fidx : -1;
        e.tcls  = (int)cls;
        e.cm    = 2.f - w * h;
        e.tc0   = gx - (float)gi;
        e.tc1   = gy - (float)gj;
        e.tc2   = logf(gw / c_aw[best]);
        e.tc3   = logf(gh / c_ah[best]);
        e.tconf = iou_sel;
        entries[b * MAXB + t] = e;
    }
    if (t == 0) {
        unsigned long long nm = ~mask;      // lanes >= 50 contribute 0 bits, nm != 0
        int cnt = __ffsll((unsigned long long)nm) - 1;  // trailing ones of mask
        nvalid[b] = min(cnt, MAXB);
    }
}

// ---------------- Kernel B: coord + conf losses over all N cells -----------
__global__ __launch_bounds__(256)
void main_kernel(const float* __restrict__ out,
                 const float4* __restrict__ gt, const int* __restrict__ nvalid,
                 const Entry* __restrict__ entries, float* __restrict__ loss) {
    int b   = blockIdx.y;
    int tid = threadIdx.x;
    int m   = blockIdx.x * blockDim.x + tid;

    __shared__ float4 sgt[MAXB];
    __shared__ Entry  sent[MAXB];
    __shared__ int    snv;
    if (tid < MAXB) {
        sgt[tid]  = gt[b * MAXB + tid];
        sent[tid] = entries[b * MAXB + tid];
    }
    if (tid == 0) snv = nvalid[b];
    __syncthreads();

    float part = 0.f;
    if (m < PER_B) {
        int a   = m / PLANE;
        int pos = m - a * PLANE;
        int j   = pos / NW;
        int i   = pos - j * NW;

        int base = ((b * NA + a) * NCH) * PLANE + pos;
        float o0 = out[base];
        float o1 = out[base + PLANE];
        float o2 = out[base + 2 * PLANE];
        float o3 = out[base + 3 * PLANE];
        float o4 = out[base + 4 * PLANE];

        float s0   = sigmoidf(o0);
        float s1   = sigmoidf(o1);
        float conf = sigmoidf(o4);
        float px = s0 + (float)i;
        float py = s1 + (float)j;
        float pw = expf(o2) * c_aw[a];
        float ph = expf(o3) * c_ah[a];

        float curmax = 0.f;
        int nv = snv;
        for (int s = 0; s < nv; s++) {
            float4 g = sgt[s];
            curmax = fmaxf(curmax, iou_f(px, py, pw, ph, g.x, g.y, g.z, g.w));
        }

        // defaults (SEEN=0 < 12800)
        float cm = 0.01f, tc0 = 0.5f, tc1 = 0.5f, tc2 = 0.f, tc3 = 0.f, tconf = 0.f;
        bool is_obj = false;
        int n = b * PER_B + m;
        for (int s = 0; s < MAXB; s++) {
            if (sent[s].fidx == n) {
                is_obj = true;
                cm  = sent[s].cm;
                tc0 = sent[s].tc0;  tc1 = sent[s].tc1;
                tc2 = sent[s].tc2;  tc3 = sent[s].tc3;
                tconf = sent[s].tconf;
            }
        }
        float conf_mask = is_obj ? 5.f : ((curmax <= 0.6f) ? 1.f : 0.f);

        float d;
        d = (s0   - tc0)   * cm;        part += d * d;
        d = (s1   - tc1)   * cm;        part += d * d;
        d = (o2   - tc2)   * cm;        part += d * d;
        d = (o3   - tc3)   * cm;        part += d * d;
        d = (conf - tconf) * conf_mask; part += d * d;
    }

    // block reduction (4 waves of 64)
    for (int off = 32; off > 0; off >>= 1) part += __shfl_down(part, off);
    __shared__ float wsum[4];
    int wid = tid >> 6, lane = tid & 63;
    if (lane == 0) wsum[wid] = part;
    __syncthreads();
    if (tid == 0) {
        float tot = wsum[0] + wsum[1] + wsum[2] + wsum[3];
        atomicAdd(loss, tot * (1.0f / NB));
    }
}

// ---------------- Kernel C: class CE at winner cells (1 wave each) ---------
__global__ __launch_bounds__(64)
void cls_kernel(const float* __restrict__ out, const Entry* __restrict__ entries,
                float* __restrict__ loss) {
    int e = blockIdx.x;            // 0 .. NB*MAXB-1
    Entry ent = entries[e];
    if (ent.fidx < 0) return;

    int b   = e / MAXB;
    int rel = ent.fidx - b * PER_B;
    int a   = rel / PLANE;
    int pos = rel - a * PLANE;
    int base = ((b * NA + a) * NCH + 5) * PLANE + pos;

    int l = threadIdx.x;
    float v1 = out[base + l * PLANE];                          // classes 0..63
    float v2 = (l < 16) ? out[base + (64 + l) * PLANE] : -INFINITY;  // 64..79

    float mx = fmaxf(v1, v2);
    for (int off = 32; off > 0; off >>= 1) mx = fmaxf(mx, __shfl_xor(mx, off));
    float s = expf(v1 - mx) + ((l < 16) ? expf(v2 - mx) : 0.f);
    for (int off = 32; off > 0; off >>= 1) s += __shfl_xor(s, off);
    float lse = mx + logf(s);

    int tc = ent.tcls;
    float tv = (tc < 64) ? __shfl(v1, tc) : __shfl(v2, tc - 64);
    if (l == 0) atomicAdd(loss, (lse - tv) * (1.0f / NB));
}

extern "C" void kernel_launch(void* const* d_in, const int* in_sizes, int n_in,
                              void* d_out, int out_size, void* d_ws, size_t ws_size,
                              hipStream_t stream) {
    const float* out    = (const float*)d_in[0];
    const float* target = (const float*)d_in[1];
    float* loss = (float*)d_out;

    char* ws = (char*)d_ws;
    float4* gt     = (float4*)ws;                 // 64*50*16 = 51200 B
    int*    nvalid = (int*)(ws + 51200);          // 256 B
    Entry*  entries = (Entry*)(ws + 51456);       // 64*50*32 = 102400 B

    hipMemsetAsync(d_out, 0, sizeof(float), stream);

    prep_kernel<<<NB, 64, 0, stream>>>(out, target, gt, nvalid, entries);

    dim3 grid((PER_B + 255) / 256, NB);
    main_kernel<<<grid, 256, 0, stream>>>(out, gt, nvalid, entries, loss);

    cls_kernel<<<NB * MAXB, 64, 0, stream>>>(out, entries, loss);
}

// Round 2
// 253.529 us; speedup vs baseline: 1.0723x; 1.0723x over previous
//
#include <hip/hip_runtime.h>
#include <math.h>

#define NB 64
#define NA 5
#define NC 80
#define NH 38
#define NW 38
#define MAXB 50
#define PLANE (NH*NW)          // 1444
#define PER_B (NA*PLANE)       // 7220
#define NCH (5+NC)             // 85
#define MAIN_BX ((PER_B + 255) / 256)   // 29
#define NPART (MAIN_BX * NB)            // 1856

__constant__ float c_aw[5] = {1.3221f, 3.19275f, 5.05587f, 9.47112f, 11.2364f};
__constant__ float c_ah[5] = {1.73145f, 4.00944f, 8.09892f, 4.84053f, 10.0071f};

struct Entry {
    int   fidx;    // global flat index into N, or -1 if not a winner
    int   tcls;
    float cm, tc0, tc1, tc2, tc3, tconf;
};

__device__ inline float sigmoidf(float x) { return 1.f / (1.f + expf(-x)); }

__device__ inline float iou_f(float ax, float ay, float aw_, float ah_,
                              float bx, float by, float bw_, float bh_) {
    float ax1 = ax - aw_ * 0.5f, ax2 = ax + aw_ * 0.5f;
    float ay1 = ay - ah_ * 0.5f, ay2 = ay + ah_ * 0.5f;
    float bx1 = bx - bw_ * 0.5f, bx2 = bx + bw_ * 0.5f;
    float by1 = by - bh_ * 0.5f, by2 = by + bh_ * 0.5f;
    float iw = fmaxf(fminf(ax2, bx2) - fmaxf(ax1, bx1), 0.f);
    float ih = fmaxf(fminf(ay2, by2) - fmaxf(ay1, by1), 0.f);
    float inter = iw * ih;
    float uni = aw_ * ah_ + bw_ * bh_ - inter;
    return inter / fmaxf(uni, 1e-10f);
}

// ---------------- Kernel A: per-batch GT prep (64 blocks x 64 threads) -----
__global__ __launch_bounds__(64)
void prep_kernel(const float* __restrict__ out, const float* __restrict__ target,
                 float4* __restrict__ gt, int* __restrict__ nvalid,
                 Entry* __restrict__ entries) {
    int b = blockIdx.x;
    int t = threadIdx.x;
    const float* tb = target + b * MAXB * 5;

    float cls = 0.f, x = 0.f, y = 0.f, w = 0.f, h = 0.f;
    bool has = (t < MAXB);
    if (has) {
        cls = tb[t * 5 + 0];
        x   = tb[t * 5 + 1];
        y   = tb[t * 5 + 2];
        w   = tb[t * 5 + 3];
        h   = tb[t * 5 + 4];
    }
    unsigned long long mask = __ballot(has && (x > 0.f));
    // valid = all boxes s<=t have x>0 (cumprod prefix)
    bool valid = has && (((~mask) & ((1ull << (t + 1)) - 1ull)) == 0ull);

    float gx = x * NW, gy = y * NH, gw = w * NW, gh = h * NH;

    // anchor argmax (first index on ties, like jnp.argmax)
    int best = 0; float bestr = -1.f;
    #pragma unroll
    for (int a = 0; a < NA; a++) {
        float inter = fminf(c_aw[a], gw) * fminf(c_ah[a], gh);
        float uni   = c_aw[a] * c_ah[a] + gw * gh - inter;
        float r = inter / fmaxf(uni, 1e-10f);
        if (r > bestr) { bestr = r; best = a; }
    }
    int gi = min(max((int)gx, 0), NW - 1);
    int gj = min(max((int)gy, 0), NH - 1);
    int fidx = b * PER_B + best * PLANE + gj * NW + gi;

    float iou_sel = 0.f;
    if (valid) {
        int base = ((b * NA + best) * NCH) * PLANE + gj * NW + gi;
        float o0 = out[base];
        float o1 = out[base + PLANE];
        float o2 = out[base + 2 * PLANE];
        float o3 = out[base + 3 * PLANE];
        float px = sigmoidf(o0) + (float)gi;
        float py = sigmoidf(o1) + (float)gj;
        float pw = expf(o2) * c_aw[best];
        float ph = expf(o3) * c_ah[best];
        iou_sel = iou_f(gx, gy, gw, gh, px, py, pw, ph);
    }

    // winner = last valid box with this fidx (numpy last-write-wins)
    __shared__ int sfidx[64];
    sfidx[t] = valid ? fidx : -1;
    __syncthreads();
    bool winner = valid;
    if (valid) {
        for (int s = t + 1; s < MAXB; s++) {
            if (sfidx[s] == fidx) { winner = false; break; }
        }
    }

    if (has) {
        gt[b * MAXB + t] = make_float4(gx, gy, gw, gh);
        Entry e;
        e.fidx  = winner ? fidx : -1;
        e.tcls  = (int)cls;
        e.cm    = 2.f - w * h;
        e.tc0   = gx - (float)gi;
        e.tc1   = gy - (float)gj;
        e.tc2   = logf(gw / c_aw[best]);
        e.tc3   = logf(gh / c_ah[best]);
        e.tconf = iou_sel;
        entries[b * MAXB + t] = e;
    }
    if (t == 0) {
        unsigned long long nm = ~mask;      // lanes >= 50 contribute 0 bits, nm != 0
        int cnt = __ffsll((unsigned long long)nm) - 1;  // trailing ones of mask
        nvalid[b] = min(cnt, MAXB);
    }
}

// -------- Kernel B: coord + conf + class losses over all N cells -----------
// One partial per block -> ws (no global atomics).
__global__ __launch_bounds__(256)
void main_kernel(const float* __restrict__ out,
                 const float4* __restrict__ gt, const int* __restrict__ nvalid,
                 const Entry* __restrict__ entries, float* __restrict__ partial) {
    int b   = blockIdx.y;
    int tid = threadIdx.x;
    int m   = blockIdx.x * blockDim.x + tid;

    __shared__ float4 sgt[MAXB];
    __shared__ Entry  sent[MAXB];
    __shared__ int    snv;
    if (tid < MAXB) {
        sgt[tid]  = gt[b * MAXB + tid];
        sent[tid] = entries[b * MAXB + tid];
    }
    if (tid == 0) snv = nvalid[b];
    __syncthreads();

    float part = 0.f;
    if (m < PER_B) {
        int a   = m / PLANE;
        int pos = m - a * PLANE;
        int j   = pos / NW;
        int i   = pos - j * NW;

        int base = ((b * NA + a) * NCH) * PLANE + pos;
        float o0 = out[base];
        float o1 = out[base + PLANE];
        float o2 = out[base + 2 * PLANE];
        float o3 = out[base + 3 * PLANE];
        float o4 = out[base + 4 * PLANE];

        float s0   = sigmoidf(o0);
        float s1   = sigmoidf(o1);
        float conf = sigmoidf(o4);
        float px = s0 + (float)i;
        float py = s1 + (float)j;
        float pw = expf(o2) * c_aw[a];
        float ph = expf(o3) * c_ah[a];

        float curmax = 0.f;
        int nv = snv;
        for (int s = 0; s < nv; s++) {
            float4 g = sgt[s];
            curmax = fmaxf(curmax, iou_f(px, py, pw, ph, g.x, g.y, g.z, g.w));
        }

        // defaults (SEEN=0 < 12800)
        float cm = 0.01f, tc0 = 0.5f, tc1 = 0.5f, tc2 = 0.f, tc3 = 0.f, tconf = 0.f;
        bool is_obj = false;
        int tcls = 0;
        int n = b * PER_B + m;
        for (int s = 0; s < MAXB; s++) {
            if (sent[s].fidx == n) {
                is_obj = true;
                cm  = sent[s].cm;
                tc0 = sent[s].tc0;  tc1 = sent[s].tc1;
                tc2 = sent[s].tc2;  tc3 = sent[s].tc3;
                tconf = sent[s].tconf;
                tcls  = sent[s].tcls;
            }
        }
        float conf_mask = is_obj ? 5.f : ((curmax <= 0.6f) ? 1.f : 0.f);

        float d;
        d = (s0   - tc0)   * cm;        part += d * d;
        d = (s1   - tc1)   * cm;        part += d * d;
        d = (o2   - tc2)   * cm;        part += d * d;
        d = (o3   - tc3)   * cm;        part += d * d;
        d = (conf - tconf) * conf_mask; part += d * d;

        // fused class cross-entropy at obj cells (~3200 of 462k threads)
        if (is_obj) {
            const float* cp = out + base + 5 * PLANE;
            float mx = -INFINITY, s = 0.f, tv = 0.f;
            for (int c = 0; c < NC; c++) {
                float v = cp[c * PLANE];
                if (c == tcls) tv = v;
                float mn = fmaxf(mx, v);
                s = s * expf(mx - mn) + expf(v - mn);
                mx = mn;
            }
            part += mx + logf(s) - tv;   // lse - logit[tcls]
        }
    }

    // block reduction (4 waves of 64)
    for (int off = 32; off > 0; off >>= 1) part += __shfl_down(part, off);
    __shared__ float wsum[4];
    int wid = tid >> 6, lane = tid & 63;
    if (lane == 0) wsum[wid] = part;
    __syncthreads();
    if (tid == 0)
        partial[b * gridDim.x + blockIdx.x] = wsum[0] + wsum[1] + wsum[2] + wsum[3];
}

// ---------------- Kernel C: final reduction (1 block), writes d_out --------
__global__ __launch_bounds__(256)
void final_kernel(const float* __restrict__ partial, float* __restrict__ loss) {
    int tid = threadIdx.x;
    float s = 0.f;
    for (int i = tid; i < NPART; i += 256) s += partial[i];
    for (int off = 32; off > 0; off >>= 1) s += __shfl_down(s, off);
    __shared__ float wsum[4];
    int wid = tid >> 6, lane = tid & 63;
    if (lane == 0) wsum[wid] = s;
    __syncthreads();
    if (tid == 0)
        loss[0] = (wsum[0] + wsum[1] + wsum[2] + wsum[3]) * (1.0f / NB);
}

extern "C" void kernel_launch(void* const* d_in, const int* in_sizes, int n_in,
                              void* d_out, int out_size, void* d_ws, size_t ws_size,
                              hipStream_t stream) {
    const float* out    = (const float*)d_in[0];
    const float* target = (const float*)d_in[1];
    float* loss = (float*)d_out;

    char* ws = (char*)d_ws;
    float4* gt      = (float4*)ws;                 // 64*50*16 = 51200 B
    int*    nvalid  = (int*)(ws + 51200);          // 256 B
    Entry*  entries = (Entry*)(ws + 51456);        // 64*50*32 = 102400 B
    float*  partial = (float*)(ws + 153856);       // 1856*4 B

    prep_kernel<<<NB, 64, 0, stream>>>(out, target, gt, nvalid, entries);

    dim3 grid(MAIN_BX, NB);
    main_kernel<<<grid, 256, 0, stream>>>(out, gt, nvalid, entries, partial);

    final_kernel<<<1, 256, 0, stream>>>(partial, loss);
}

// Round 3
// 231.794 us; speedup vs baseline: 1.1728x; 1.0938x over previous
//
#include <hip/hip_runtime.h>
#include <math.h>

#define NB 64
#define NA 5
#define NC 80
#define NH 38
#define NW 38
#define MAXB 50
#define PLANE (NH*NW)          // 1444
#define PER_B (NA*PLANE)       // 7220
#define NCH (5+NC)             // 85
#define MAIN_BX ((PER_B + 255) / 256)   // 29
#define NPART (MAIN_BX * NB)            // 1856

__constant__ float c_aw[5] = {1.3221f, 3.19275f, 5.05587f, 9.47112f, 11.2364f};
__constant__ float c_ah[5] = {1.73145f, 4.00944f, 8.09892f, 4.84053f, 10.0071f};

struct Entry {
    int   fidx;    // global flat index into N, or -1 if not a winner
    int   tcls;
    float cm, tc0, tc1, tc2, tc3, tconf;
};

__device__ inline float sigmoidf(float x) { return 1.f / (1.f + expf(-x)); }

// ---- Fused kernel: per-block wave-0 GT prep (LDS) + coord/conf/cls loss ----
__global__ __launch_bounds__(256)
void main_kernel(const float* __restrict__ out, const float* __restrict__ target,
                 float* __restrict__ partial) {
    const int b   = blockIdx.y;
    const int bx  = blockIdx.x;
    const int tid = threadIdx.x;

    __shared__ float4 sbox[MAXB];   // gt corners: x1,y1,x2,y2
    __shared__ float  sarea[MAXB];  // gt area
    __shared__ Entry  sent[MAXB];
    __shared__ int    sfx[64];
    __shared__ int    snv;
    __shared__ int    sobj_cnt;
    __shared__ int    sobj_idx[MAXB];

    if (tid == 0) sobj_cnt = 0;

    // ---------------- wave-0 prep (redundant per block, all in LDS) --------
    if (tid < 64) {
        const float* tb = target + b * MAXB * 5;
        int t = tid;
        bool has = (t < MAXB);
        float cls = 0.f, x = 0.f, y = 0.f, w = 0.f, h = 0.f;
        if (has) {
            cls = tb[t * 5 + 0];
            x   = tb[t * 5 + 1];
            y   = tb[t * 5 + 2];
            w   = tb[t * 5 + 3];
            h   = tb[t * 5 + 4];
        }
        unsigned long long mask = __ballot(has && (x > 0.f));
        bool valid = has && (((~mask) & ((1ull << (t + 1)) - 1ull)) == 0ull);

        float gx = x * NW, gy = y * NH, gw = w * NW, gh = h * NH;

        int best = 0; float bestr = -1.f;
        #pragma unroll
        for (int a = 0; a < NA; a++) {
            float inter = fminf(c_aw[a], gw) * fminf(c_ah[a], gh);
            float uni   = c_aw[a] * c_ah[a] + gw * gh - inter;
            float r = inter / fmaxf(uni, 1e-10f);
            if (r > bestr) { bestr = r; best = a; }
        }
        int gi = min(max((int)gx, 0), NW - 1);
        int gj = min(max((int)gy, 0), NH - 1);
        int fidx = b * PER_B + best * PLANE + gj * NW + gi;

        float iou_sel = 0.f;
        if (valid) {
            int base = ((b * NA + best) * NCH) * PLANE + gj * NW + gi;
            float o0 = out[base];
            float o1 = out[base + PLANE];
            float o2 = out[base + 2 * PLANE];
            float o3 = out[base + 3 * PLANE];
            float px = sigmoidf(o0) + (float)gi;
            float py = sigmoidf(o1) + (float)gj;
            float pw = expf(o2) * c_aw[best];
            float ph = expf(o3) * c_ah[best];
            float iw = fmaxf(fminf(gx + gw*0.5f, px + pw*0.5f) - fmaxf(gx - gw*0.5f, px - pw*0.5f), 0.f);
            float ih = fmaxf(fminf(gy + gh*0.5f, py + ph*0.5f) - fmaxf(gy - gh*0.5f, py - ph*0.5f), 0.f);
            float inter = iw * ih;
            float uni = gw * gh + pw * ph - inter;
            iou_sel = inter / fmaxf(uni, 1e-10f);
        }

        // winner = last valid box with this fidx (wave-lockstep LDS: in-order
        // DS pipe guarantees the write below completes before the reads)
        sfx[t] = valid ? fidx : -1;
        bool winner = valid;
        if (valid) {
            for (int s = t + 1; s < MAXB; s++)
                if (sfx[s] == fidx) { winner = false; break; }
        }

        if (has) {
            sbox[t]  = make_float4(gx - gw*0.5f, gy - gh*0.5f, gx + gw*0.5f, gy + gh*0.5f);
            sarea[t] = gw * gh;
            Entry e;
            e.fidx  = winner ? fidx : -1;
            e.tcls  = (int)cls;
            e.cm    = 2.f - w * h;
            e.tc0   = gx - (float)gi;
            e.tc1   = gy - (float)gj;
            e.tc2   = logf(gw / c_aw[best]);
            e.tc3   = logf(gh / c_ah[best]);
            e.tconf = iou_sel;
            sent[t] = e;
        }
        if (t == 0) {
            unsigned long long nm = ~mask;
            snv = min(__ffsll((unsigned long long)nm) - 1, MAXB);
        }
    }
    __syncthreads();

    // ---------------- block-local obj (winner) list -------------------------
    const int nlo = b * PER_B + bx * 256;   // this block covers n in [nlo, nlo+256)
    if (tid < MAXB) {
        int f = sent[tid].fidx;
        if (f >= nlo && f < nlo + 256) {
            int slot = atomicAdd(&sobj_cnt, 1);
            sobj_idx[slot] = tid;
        }
    }
    __syncthreads();

    // ---------------- per-cell loss -----------------------------------------
    int m = bx * 256 + tid;
    float part = 0.f;
    if (m < PER_B) {
        int a   = m / PLANE;
        int pos = m - a * PLANE;
        int j   = pos / NW;
        int i   = pos - j * NW;

        int base = ((b * NA + a) * NCH) * PLANE + pos;
        float o0 = out[base];
        float o1 = out[base + PLANE];
        float o2 = out[base + 2 * PLANE];
        float o3 = out[base + 3 * PLANE];
        float o4 = out[base + 4 * PLANE];

        float s0   = sigmoidf(o0);
        float s1   = sigmoidf(o1);
        float conf = sigmoidf(o4);
        float pw = expf(o2) * c_aw[a];
        float ph = expf(o3) * c_ah[a];
        float px1 = s0 + (float)i - pw * 0.5f;
        float px2 = px1 + pw;
        float py1 = s1 + (float)j - ph * 0.5f;
        float py2 = py1 + ph;
        float area_p = pw * ph;

        // any GT box with IoU > 0.6?  (division-free: inter > 0.6*max(uni,eps))
        bool gt06 = false;
        int nv = snv;
        for (int s = 0; s < nv; s++) {
            float4 g = sbox[s];
            float iw = fmaxf(fminf(px2, g.z) - fmaxf(px1, g.x), 0.f);
            float ih = fmaxf(fminf(py2, g.w) - fmaxf(py1, g.y), 0.f);
            float inter = iw * ih;
            float uni = area_p + sarea[s] - inter;
            gt06 = gt06 || (inter > 0.6f * fmaxf(uni, 1e-10f));
        }

        // defaults (SEEN=0 < 12800)
        float cm = 0.01f, tc0 = 0.5f, tc1 = 0.5f, tc2 = 0.f, tc3 = 0.f, tconf = 0.f;
        bool is_obj = false;
        int tcls = 0;
        int n = nlo + tid;
        int oc = sobj_cnt;
        for (int s = 0; s < oc; s++) {
            int e = sobj_idx[s];
            if (sent[e].fidx == n) {
                is_obj = true;
                cm  = sent[e].cm;
                tc0 = sent[e].tc0;  tc1 = sent[e].tc1;
                tc2 = sent[e].tc2;  tc3 = sent[e].tc3;
                tconf = sent[e].tconf;
                tcls  = sent[e].tcls;
            }
        }
        float conf_mask = is_obj ? 5.f : (gt06 ? 0.f : 1.f);

        float d;
        d = (s0   - tc0)   * cm;        part += d * d;
        d = (s1   - tc1)   * cm;        part += d * d;
        d = (o2   - tc2)   * cm;        part += d * d;
        d = (o3   - tc3)   * cm;        part += d * d;
        d = (conf - tconf) * conf_mask; part += d * d;

        // fused class cross-entropy at obj cells (~1-3 threads per block)
        if (is_obj) {
            const float* cp = out + base + 5 * PLANE;
            float mx = -INFINITY, s = 0.f, tv = 0.f;
            for (int c = 0; c < NC; c++) {
                float v = cp[c * PLANE];
                if (c == tcls) tv = v;
                float mn = fmaxf(mx, v);
                s = s * expf(mx - mn) + expf(v - mn);
                mx = mn;
            }
            part += mx + logf(s) - tv;   // lse - logit[tcls]
        }
    }

    // block reduction (4 waves of 64)
    for (int off = 32; off > 0; off >>= 1) part += __shfl_down(part, off);
    __shared__ float wsum[4];
    int wid = tid >> 6, lane = tid & 63;
    if (lane == 0) wsum[wid] = part;
    __syncthreads();
    if (tid == 0)
        partial[b * MAIN_BX + bx] = wsum[0] + wsum[1] + wsum[2] + wsum[3];
}

// ---------------- final reduction (1 block), writes d_out -------------------
__global__ __launch_bounds__(256)
void final_kernel(const float* __restrict__ partial, float* __restrict__ loss) {
    int tid = threadIdx.x;
    float s = 0.f;
    for (int i = tid; i < NPART; i += 256) s += partial[i];
    for (int off = 32; off > 0; off >>= 1) s += __shfl_down(s, off);
    __shared__ float wsum[4];
    int wid = tid >> 6, lane = tid & 63;
    if (lane == 0) wsum[wid] = s;
    __syncthreads();
    if (tid == 0)
        loss[0] = (wsum[0] + wsum[1] + wsum[2] + wsum[3]) * (1.0f / NB);
}

extern "C" void kernel_launch(void* const* d_in, const int* in_sizes, int n_in,
                              void* d_out, int out_size, void* d_ws, size_t ws_size,
                              hipStream_t stream) {
    const float* out    = (const float*)d_in[0];
    const float* target = (const float*)d_in[1];
    float* loss    = (float*)d_out;
    float* partial = (float*)d_ws;     // NPART floats

    dim3 grid(MAIN_BX, NB);
    main_kernel<<<grid, 256, 0, stream>>>(out, target, partial);
    final_kernel<<<1, 256, 0, stream>>>(partial, loss);
}